// Round 9
// baseline (362.523 us; speedup 1.0000x reference)
//
#include <hip/hip_runtime.h>

#define B_   8
#define S_   4096
#define D_   1024
#define M_   (B_ * S_)   // 32768 rows
#define N_   (2 * D_)    // 2048 cols (hidden | gate)
#define K_   D_          // 1024
#define CCH  128         // scan chunks
#define LCH  32          // chunk length (CCH*LCH == S_)

#define BK   32
#define NT   (K_ / BK)   // 32 k-tiles

typedef __attribute__((ext_vector_type(8))) short bf16x8;
typedef __attribute__((ext_vector_type(4))) float f32x4;

__device__ __forceinline__ unsigned short f2bf(float f) {
  union { float f; unsigned u; } v; v.f = f;
  unsigned u = v.u;
  u = u + 0x7fffu + ((u >> 16) & 1u);   // RNE
  return (unsigned short)(u >> 16);
}
__device__ __forceinline__ float bf2f(unsigned short h) {
  union { unsigned u; float f; } v; v.u = ((unsigned)h) << 16;
  return v.f;
}
__device__ __forceinline__ float sigmoidf_(float x) {
  return 1.0f / (1.0f + __expf(-x));
}

#define GLL(src, dst) __builtin_amdgcn_global_load_lds(                     \
      (const __attribute__((address_space(1))) void*)(src),                 \
      (__attribute__((address_space(3))) void*)(dst), 16, 0, 0)

// ---------- fp32 -> bf16 convert, x and W in one launch ----------
__global__ __launch_bounds__(256) void k_cvt2(const float* __restrict__ x,
                                              const float* __restrict__ W,
                                              unsigned short* __restrict__ xb,
                                              unsigned short* __restrict__ wb) {
  const int n4x = (M_ * K_) / 4;             // 8388608
  const int n4t = n4x + (N_ * K_) / 4;       // + 524288
  int i = blockIdx.x * 256 + threadIdx.x;
  const int stride = gridDim.x * 256;
  for (; i < n4t; i += stride) {
    const float4* src = (i < n4x) ? &reinterpret_cast<const float4*>(x)[i]
                                  : &reinterpret_cast<const float4*>(W)[i - n4x];
    float4 v = *src;
    ushort4 o;
    o.x = f2bf(v.x); o.y = f2bf(v.y); o.z = f2bf(v.z); o.w = f2bf(v.w);
    if (i < n4x) reinterpret_cast<ushort4*>(xb)[i] = o;
    else         reinterpret_cast<ushort4*>(wb)[i - n4x] = o;
  }
}

// ---------- bf16 GEMM + fused chunk-scan epilogue --------------------------
// R9: B-tile pairs hidden+gate columns (64 W-rows from each half; same staged
// bytes, same 16 MFMA/tile: accH[4][2] + accG[4][2]). Epilogue computes the
// per-chunk (32-step) scan in-register: 4-elem segments per lane, 2-step
// Hillis-Steele compose across hi-groups via __shfl, replay; writes hl
// (local h) + ap (prefix prod a) bf16 planes with NT stores. Eliminates the
// scan1 pass (128 MB re-read). Core K-loop identical to R8 (vmcnt(3) ring,
// pair-row swizzle = 0 conflicts, 2 WG/CU, XCD swizzle, setprio).
__global__ __launch_bounds__(512, 4) void k_gemm(const unsigned short* __restrict__ xb,
                                                 const unsigned short* __restrict__ wb,
                                                 unsigned short* __restrict__ HLp,
                                                 unsigned short* __restrict__ APp) {
  // 3 slots x (A 256x32 16KB | B 128x32 8KB) = 72 KiB
  __shared__ unsigned short lds[36864];
  const int tid = threadIdx.x;
  int wg = blockIdx.x;
  wg = (wg & 7) * 256 + (wg >> 3);     // XCD swizzle; 2048 % 8 == 0 -> bijective
  const int bm = wg >> 4;              // 0..127  (256-row panels)
  const int bn = wg & 15;              // 0..15   (64-d-col panels, paired)
  const int lane = tid & 63;
  const int wid = tid >> 6;            // 0..7
  const int wrr = wid >> 1;            // 0..3 (64-row band)
  const int wcc = wid & 1;             // 0..1 (32-d-col band)
  const int fr = lane & 15;
  const int hi = lane >> 4;            // 0..3

  // staging: srow = tid>>2 (0..127), slot i = tid&3; LDS dest linear tid*16;
  // fetch logical blk j = i ^ ((srow>>1)&3) (pair-row swizzle, R7-verified).
  const int srow = tid >> 2;
  const int scol = ((tid & 3) ^ ((srow >> 1) & 3)) * 16;
  const char* aS = (const char*)xb + (size_t)(bm * 256 + srow) * 2048 + scol;
  // B rows: srow<64 -> hidden e = bn*64+srow ; srow>=64 -> gate e = 1024+bn*64+srow-64
  const char* bS = (const char*)wb +
      (size_t)(bn * 64 + srow + ((srow >= 64) ? 960 : 0)) * 2048 + scol;
  char* const ldsc = (char*)lds + (size_t)tid * 16;   // per-thread stage dest
  const char* const ldsr = (const char*)lds;          // read base

  const int sA = ((hi ^ ((fr >> 1) & 3)) * 16);
  const int arow  = (wrr * 64 + fr) * 64;             // A byte row base (m=0)
  const int browH = 16384 + (wcc * 32 + fr) * 64;     // B hidden rows
  const int browG = browH + 4096;                     // B gate rows (+64 rows)

  f32x4 accH[4][2] = {};
  f32x4 accG[4][2] = {};
  bf16x8 av[4], bvH[2], bvG[2];

  // prologue: tile0 -> slot0, tile1 -> slot1 (6 GLL in flight), wait oldest 3
  GLL(aS,               ldsc);           // t0 A rows 0-127
  GLL(aS + 262144,      ldsc + 8192);    // t0 A rows 128-255
  GLL(bS,               ldsc + 16384);   // t0 B (paired)
  GLL(aS + 64,          ldsc + 24576);
  GLL(aS + 262144 + 64, ldsc + 32768);
  GLL(bS + 64,          ldsc + 40960);
  asm volatile("s_waitcnt vmcnt(3)\n\ts_barrier" ::: "memory");

  int sl = 0;       // read slot byte base
  int sn = 49152;   // stage slot byte base (slot 2)

  for (int t = 0; t < NT; ++t) {
    const bool st2 = (t < NT - 2);
    if (st2) {      // stage tile t+2 into freed slot
      const size_t kb = (size_t)(t + 2) * 64;
      char* dq = ldsc + sn;
      GLL(aS + kb,          dq);
      GLL(aS + 262144 + kb, dq + 8192);
      GLL(bS + kb,          dq + 16384);
    }
    const char* Ab = ldsr + sl;
#pragma unroll
    for (int m = 0; m < 4; ++m)
      av[m] = *(const bf16x8*)(Ab + arow + m * 1024 + sA);
#pragma unroll
    for (int n = 0; n < 2; ++n) {
      bvH[n] = *(const bf16x8*)(Ab + browH + n * 1024 + sA);
      bvG[n] = *(const bf16x8*)(Ab + browG + n * 1024 + sA);
    }
    __builtin_amdgcn_s_setprio(1);
#pragma unroll
    for (int m = 0; m < 4; ++m) {
#pragma unroll
      for (int n = 0; n < 2; ++n) {
        accH[m][n] = __builtin_amdgcn_mfma_f32_16x16x32_bf16(av[m], bvH[n], accH[m][n], 0, 0, 0);
        accG[m][n] = __builtin_amdgcn_mfma_f32_16x16x32_bf16(av[m], bvG[n], accG[m][n], 0, 0, 0);
      }
    }
    __builtin_amdgcn_s_setprio(0);
    if (st2) asm volatile("s_waitcnt vmcnt(3)\n\ts_barrier" ::: "memory");
    else     asm volatile("s_waitcnt vmcnt(0)\n\ts_barrier" ::: "memory");
    sl += 24576; if (sl == 73728) sl = 0;
    sn += 24576; if (sn == 73728) sn = 0;
  }

  // ---- fused epilogue: per-chunk (32-step) scan; writes hl/ap bf16 planes.
  // C/D layout: col = lane&15 (d), row = (lane>>4)*4 + reg (s)  [m89-verified]
  // s_rel within 64-row band = m*16 + hi*4 + i; chunk kap = m>>1.
  const int dcol0 = bn * 64 + wcc * 32 + fr;
  const size_t rowg0 = (size_t)(bm * 256 + wrr * 64);
#pragma unroll
  for (int kap = 0; kap < 2; ++kap) {
#pragma unroll
    for (int n = 0; n < 2; ++n) {
      float a_[2][4], b_[2][4];
#pragma unroll
      for (int mm = 0; mm < 2; ++mm)
#pragma unroll
        for (int i = 0; i < 4; ++i) {
          float zg = sigmoidf_(accG[kap * 2 + mm][n][i]);
          float hv = accH[kap * 2 + mm][n][i];
          float gg = (hv >= 0.f) ? (hv + 0.5f) : sigmoidf_(hv);
          a_[mm][i] = 1.f - zg;
          b_[mm][i] = zg * gg;
        }
      // per-lane 4-step segment transforms T(h)=A*h+B (s-order: i ascending)
      float A1 = a_[0][0] * a_[0][1] * a_[0][2] * a_[0][3];
      float B1 = ((b_[0][0] * a_[0][1] + b_[0][1]) * a_[0][2] + b_[0][2]) * a_[0][3] + b_[0][3];
      float A2 = a_[1][0] * a_[1][1] * a_[1][2] * a_[1][3];
      float B2 = ((b_[1][0] * a_[1][1] + b_[1][1]) * a_[1][2] + b_[1][2]) * a_[1][3] + b_[1][3];
      // Hillis-Steele inclusive compose across hi (segments ordered by hi)
      float Ai = A1, Bi = B1;
      { float Ao = __shfl(Ai, (lane - 16) & 63), Bo = __shfl(Bi, (lane - 16) & 63);
        if (hi >= 1) { Bi += Ai * Bo; Ai *= Ao; } }
      { float Ao = __shfl(Ai, (lane - 32) & 63), Bo = __shfl(Bi, (lane - 32) & 63);
        if (hi >= 2) { Bi += Ai * Bo; Ai *= Ao; } }
      float Ae1 = __shfl(Ai, (lane - 16) & 63), Be1 = __shfl(Bi, (lane - 16) & 63);
      if (hi == 0) { Ae1 = 1.f; Be1 = 0.f; }
      float At = __shfl(Ai, fr + 48), Bt = __shfl(Bi, fr + 48);  // total of s0..15
      float Ai2 = A2, Bi2 = B2;
      { float Ao = __shfl(Ai2, (lane - 16) & 63), Bo = __shfl(Bi2, (lane - 16) & 63);
        if (hi >= 1) { Bi2 += Ai2 * Bo; Ai2 *= Ao; } }
      { float Ao = __shfl(Ai2, (lane - 32) & 63), Bo = __shfl(Bi2, (lane - 32) & 63);
        if (hi >= 2) { Bi2 += Ai2 * Bo; Ai2 *= Ao; } }
      float Ae2 = __shfl(Ai2, (lane - 16) & 63), Be2 = __shfl(Bi2, (lane - 16) & 63);
      if (hi == 0) { Ae2 = 1.f; Be2 = 0.f; }
      const float Ax2 = Ae2 * At;            // prefix for mm=1 seg = excl2 ∘ total1
      const float Bx2 = Be2 + Ae2 * Bt;
      // replay + NT-store hl/ap per position
      const int d = dcol0 + n * 16;
      size_t rr = (rowg0 + kap * 32 + hi * 4) * 1024 + d;
      float ap = Ae1, hl = Be1;
#pragma unroll
      for (int i = 0; i < 4; ++i) {
        hl = a_[0][i] * hl + b_[0][i]; ap *= a_[0][i];
        __builtin_nontemporal_store(f2bf(hl), &HLp[rr]);
        __builtin_nontemporal_store(f2bf(ap), &APp[rr]);
        rr += 1024;
      }
      rr = (rowg0 + kap * 32 + 16 + hi * 4) * 1024 + d;
      ap = Ax2; hl = Bx2;
#pragma unroll
      for (int i = 0; i < 4; ++i) {
        hl = a_[1][i] * hl + b_[1][i]; ap *= a_[1][i];
        __builtin_nontemporal_store(f2bf(hl), &HLp[rr]);
        __builtin_nontemporal_store(f2bf(ap), &APp[rr]);
        rr += 1024;
      }
    }
  }
}

// ---------- scan phase 2: carry chain over chunk totals --------------------
// Chunk totals ARE the s==31 elements of hl/ap. Rewrites HL[s=31] with the
// inclusive carry H[c] (= final output at s=31; = carry for chunk c+1).
__global__ __launch_bounds__(256) void k_scan2(unsigned short* __restrict__ HL,
                                               const unsigned short* __restrict__ AP) {
  const int gid = blockIdx.x * 256 + threadIdx.x;   // 0..2047
  const int b = gid >> 8;
  const int d0 = (gid & 255) << 2;
  float c0 = 0.f, c1 = 0.f, c2 = 0.f, c3 = 0.f;
  for (int c = 0; c < CCH; ++c) {
    size_t off = ((size_t)b * S_ + (size_t)c * LCH + 31) * 1024 + d0;
    ushort4 hu = *reinterpret_cast<const ushort4*>(HL + off);
    ushort4 au = *reinterpret_cast<const ushort4*>(AP + off);
    c0 = fmaf(bf2f(au.x), c0, bf2f(hu.x));
    c1 = fmaf(bf2f(au.y), c1, bf2f(hu.y));
    c2 = fmaf(bf2f(au.z), c2, bf2f(hu.z));
    c3 = fmaf(bf2f(au.w), c3, bf2f(hu.w));
    ushort4 o; o.x = f2bf(c0); o.y = f2bf(c1); o.z = f2bf(c2); o.w = f2bf(c3);
    *reinterpret_cast<ushort4*>(HL + off) = o;
  }
}

// ---------- scan phase 3: out = hl + ap * carry ----------------------------
__global__ __launch_bounds__(256) void k_scan3(const unsigned short* __restrict__ HL,
                                               const unsigned short* __restrict__ AP,
                                               float* __restrict__ out) {
  const int gid = blockIdx.x * 256 + threadIdx.x;
  const int c = blockIdx.y;
  const int b = gid >> 8;
  const int d0 = (gid & 255) << 2;
  const size_t rbase = (size_t)b * S_ + (size_t)c * LCH;
  float4 carry = {0.f, 0.f, 0.f, 0.f};
  if (c > 0) {
    ushort4 cu = *reinterpret_cast<const ushort4*>(HL + (rbase - 1) * 1024 + d0);
    carry.x = bf2f(cu.x); carry.y = bf2f(cu.y); carry.z = bf2f(cu.z); carry.w = bf2f(cu.w);
  }
  size_t off = rbase * 1024 + d0;
#pragma unroll 8
  for (int s = 0; s < LCH - 1; ++s) {
    ushort4 hu = *reinterpret_cast<const ushort4*>(HL + off);
    ushort4 au = *reinterpret_cast<const ushort4*>(AP + off);
    float4 o;
    o.x = fmaf(bf2f(au.x), carry.x, bf2f(hu.x));
    o.y = fmaf(bf2f(au.y), carry.y, bf2f(hu.y));
    o.z = fmaf(bf2f(au.z), carry.z, bf2f(hu.z));
    o.w = fmaf(bf2f(au.w), carry.w, bf2f(hu.w));
    *reinterpret_cast<float4*>(out + off) = o;
    off += 1024;
  }
  // s == 31: HL already holds the final (inclusive-carry) value from k_scan2
  ushort4 hu = *reinterpret_cast<const ushort4*>(HL + off);
  float4 o;
  o.x = bf2f(hu.x); o.y = bf2f(hu.y); o.z = bf2f(hu.z); o.w = bf2f(hu.w);
  *reinterpret_cast<float4*>(out + off) = o;
}

extern "C" void kernel_launch(void* const* d_in, const int* in_sizes, int n_in,
                              void* d_out, int out_size, void* d_ws, size_t ws_size,
                              hipStream_t stream) {
  const float* x = (const float*)d_in[0];   // [8,4096,1024] f32
  const float* W = (const float*)d_in[1];   // [2048,1024]  f32
  float* out = (float*)d_out;               // [8,4096,1024] f32

  unsigned char* w = (unsigned char*)d_ws;
  // layout (= R8's proven 196 MiB): xb(64MB) | wb(4MB) | HL(64MB) | AP(64MB)
  unsigned short* xb  = (unsigned short*)(w);
  unsigned short* wb  = (unsigned short*)(w + 67108864);
  unsigned short* HLp = (unsigned short*)(w + 71303168);
  unsigned short* APp = (unsigned short*)(w + 138412032);

  k_cvt2<<<4096, 256, 0, stream>>>(x, W, xb, wb);
  k_gemm<<<(M_ / 256) * 16, 512, 0, stream>>>(xb, wb, HLp, APp);
  k_scan2<<<8, 256, 0, stream>>>(HLp, APp);
  k_scan3<<<dim3(8, CCH), 256, 0, stream>>>(HLp, APp, out);
}

// Round 10
// 288.239 us; speedup vs baseline: 1.2577x; 1.2577x over previous
//
#include <hip/hip_runtime.h>

#define B_   8
#define S_   4096
#define D_   1024
#define M_   (B_ * S_)   // 32768 rows
#define N_   (2 * D_)    // 2048 cols (hidden | gate)
#define K_   D_          // 1024
#define CCH  128         // scan chunks
#define LCH  32          // chunk length (CCH*LCH == S_)

#define BK   32
#define NT   (K_ / BK)   // 32 k-tiles

typedef __attribute__((ext_vector_type(8))) short bf16x8;
typedef __attribute__((ext_vector_type(4))) float f32x4;

__device__ __forceinline__ unsigned short f2bf(float f) {
  union { float f; unsigned u; } v; v.f = f;
  unsigned u = v.u;
  u = u + 0x7fffu + ((u >> 16) & 1u);   // RNE
  return (unsigned short)(u >> 16);
}
__device__ __forceinline__ float bf2f(unsigned short h) {
  union { unsigned u; float f; } v; v.u = ((unsigned)h) << 16;
  return v.f;
}
__device__ __forceinline__ float sigmoidf_(float x) {
  return 1.0f / (1.0f + __expf(-x));
}

#define GLL(src, dst) __builtin_amdgcn_global_load_lds(                     \
      (const __attribute__((address_space(1))) void*)(src),                 \
      (__attribute__((address_space(3))) void*)(dst), 16, 0, 0)

// ---------- fp32 -> bf16 convert, x and W in one launch ----------
__global__ __launch_bounds__(256) void k_cvt2(const float* __restrict__ x,
                                              const float* __restrict__ W,
                                              unsigned short* __restrict__ xb,
                                              unsigned short* __restrict__ wb) {
  const int n4x = (M_ * K_) / 4;             // 8388608
  const int n4t = n4x + (N_ * K_) / 4;       // + 524288
  int i = blockIdx.x * 256 + threadIdx.x;
  const int stride = gridDim.x * 256;
  for (; i < n4t; i += stride) {
    const float4* src = (i < n4x) ? &reinterpret_cast<const float4*>(x)[i]
                                  : &reinterpret_cast<const float4*>(W)[i - n4x];
    float4 v = *src;
    ushort4 o;
    o.x = f2bf(v.x); o.y = f2bf(v.y); o.z = f2bf(v.z); o.w = f2bf(v.w);
    if (i < n4x) reinterpret_cast<ushort4*>(xb)[i] = o;
    else         reinterpret_cast<ushort4*>(wb)[i - n4x] = o;
  }
}

// ---------- bf16 GEMM + fused chunk-scan epilogue --------------------------
// R10 = R9 with PLAIN stores in the epilogue (NT stores caused partial-line
// HBM writes: +46MB WRITE_SIZE, vmcnt-retirement stall, -60us; plain stores
// merge 32B segments into full lines in L2). Everything else unchanged:
// paired hidden+gate B-tile, in-register chunk scan (4-elem segments +
// 2-step shfl Hillis-Steele), hl/ap bf16 planes; K-loop = R8's proven
// vmcnt(3) ring, pair-row swizzle (0 conflicts), 2 WG/CU, XCD swizzle.
__global__ __launch_bounds__(512, 4) void k_gemm(const unsigned short* __restrict__ xb,
                                                 const unsigned short* __restrict__ wb,
                                                 unsigned short* __restrict__ HLp,
                                                 unsigned short* __restrict__ APp) {
  // 3 slots x (A 256x32 16KB | B 128x32 8KB) = 72 KiB
  __shared__ unsigned short lds[36864];
  const int tid = threadIdx.x;
  int wg = blockIdx.x;
  wg = (wg & 7) * 256 + (wg >> 3);     // XCD swizzle; 2048 % 8 == 0 -> bijective
  const int bm = wg >> 4;              // 0..127  (256-row panels)
  const int bn = wg & 15;              // 0..15   (64-d-col panels, paired)
  const int lane = tid & 63;
  const int wid = tid >> 6;            // 0..7
  const int wrr = wid >> 1;            // 0..3 (64-row band)
  const int wcc = wid & 1;             // 0..1 (32-d-col band)
  const int fr = lane & 15;
  const int hi = lane >> 4;            // 0..3

  // staging: srow = tid>>2 (0..127), slot i = tid&3; LDS dest linear tid*16;
  // fetch logical blk j = i ^ ((srow>>1)&3) (pair-row swizzle, R7-verified).
  const int srow = tid >> 2;
  const int scol = ((tid & 3) ^ ((srow >> 1) & 3)) * 16;
  const char* aS = (const char*)xb + (size_t)(bm * 256 + srow) * 2048 + scol;
  // B rows: srow<64 -> hidden e = bn*64+srow ; srow>=64 -> gate e = 1024+bn*64+srow-64
  const char* bS = (const char*)wb +
      (size_t)(bn * 64 + srow + ((srow >= 64) ? 960 : 0)) * 2048 + scol;
  char* const ldsc = (char*)lds + (size_t)tid * 16;   // per-thread stage dest
  const char* const ldsr = (const char*)lds;          // read base

  const int sA = ((hi ^ ((fr >> 1) & 3)) * 16);
  const int arow  = (wrr * 64 + fr) * 64;             // A byte row base (m=0)
  const int browH = 16384 + (wcc * 32 + fr) * 64;     // B hidden rows
  const int browG = browH + 4096;                     // B gate rows (+64 rows)

  f32x4 accH[4][2] = {};
  f32x4 accG[4][2] = {};
  bf16x8 av[4], bvH[2], bvG[2];

  // prologue: tile0 -> slot0, tile1 -> slot1 (6 GLL in flight), wait oldest 3
  GLL(aS,               ldsc);           // t0 A rows 0-127
  GLL(aS + 262144,      ldsc + 8192);    // t0 A rows 128-255
  GLL(bS,               ldsc + 16384);   // t0 B (paired)
  GLL(aS + 64,          ldsc + 24576);
  GLL(aS + 262144 + 64, ldsc + 32768);
  GLL(bS + 64,          ldsc + 40960);
  asm volatile("s_waitcnt vmcnt(3)\n\ts_barrier" ::: "memory");

  int sl = 0;       // read slot byte base
  int sn = 49152;   // stage slot byte base (slot 2)

  for (int t = 0; t < NT; ++t) {
    const bool st2 = (t < NT - 2);
    if (st2) {      // stage tile t+2 into freed slot
      const size_t kb = (size_t)(t + 2) * 64;
      char* dq = ldsc + sn;
      GLL(aS + kb,          dq);
      GLL(aS + 262144 + kb, dq + 8192);
      GLL(bS + kb,          dq + 16384);
    }
    const char* Ab = ldsr + sl;
#pragma unroll
    for (int m = 0; m < 4; ++m)
      av[m] = *(const bf16x8*)(Ab + arow + m * 1024 + sA);
#pragma unroll
    for (int n = 0; n < 2; ++n) {
      bvH[n] = *(const bf16x8*)(Ab + browH + n * 1024 + sA);
      bvG[n] = *(const bf16x8*)(Ab + browG + n * 1024 + sA);
    }
    __builtin_amdgcn_s_setprio(1);
#pragma unroll
    for (int m = 0; m < 4; ++m) {
#pragma unroll
      for (int n = 0; n < 2; ++n) {
        accH[m][n] = __builtin_amdgcn_mfma_f32_16x16x32_bf16(av[m], bvH[n], accH[m][n], 0, 0, 0);
        accG[m][n] = __builtin_amdgcn_mfma_f32_16x16x32_bf16(av[m], bvG[n], accG[m][n], 0, 0, 0);
      }
    }
    __builtin_amdgcn_s_setprio(0);
    if (st2) asm volatile("s_waitcnt vmcnt(3)\n\ts_barrier" ::: "memory");
    else     asm volatile("s_waitcnt vmcnt(0)\n\ts_barrier" ::: "memory");
    sl += 24576; if (sl == 73728) sl = 0;
    sn += 24576; if (sn == 73728) sn = 0;
  }

  // ---- fused epilogue: per-chunk (32-step) scan; writes hl/ap bf16 planes.
  // C/D layout: col = lane&15 (d), row = (lane>>4)*4 + reg (s)  [m89-verified]
  // s_rel within 64-row band = m*16 + hi*4 + i; chunk kap = m>>1.
  const int dcol0 = bn * 64 + wcc * 32 + fr;
  const size_t rowg0 = (size_t)(bm * 256 + wrr * 64);
#pragma unroll
  for (int kap = 0; kap < 2; ++kap) {
#pragma unroll
    for (int n = 0; n < 2; ++n) {
      float a_[2][4], b_[2][4];
#pragma unroll
      for (int mm = 0; mm < 2; ++mm)
#pragma unroll
        for (int i = 0; i < 4; ++i) {
          float zg = sigmoidf_(accG[kap * 2 + mm][n][i]);
          float hv = accH[kap * 2 + mm][n][i];
          float gg = (hv >= 0.f) ? (hv + 0.5f) : sigmoidf_(hv);
          a_[mm][i] = 1.f - zg;
          b_[mm][i] = zg * gg;
        }
      // per-lane 4-step segment transforms T(h)=A*h+B (s-order: i ascending)
      float A1 = a_[0][0] * a_[0][1] * a_[0][2] * a_[0][3];
      float B1 = ((b_[0][0] * a_[0][1] + b_[0][1]) * a_[0][2] + b_[0][2]) * a_[0][3] + b_[0][3];
      float A2 = a_[1][0] * a_[1][1] * a_[1][2] * a_[1][3];
      float B2 = ((b_[1][0] * a_[1][1] + b_[1][1]) * a_[1][2] + b_[1][2]) * a_[1][3] + b_[1][3];
      // Hillis-Steele inclusive compose across hi (segments ordered by hi)
      float Ai = A1, Bi = B1;
      { float Ao = __shfl(Ai, (lane - 16) & 63), Bo = __shfl(Bi, (lane - 16) & 63);
        if (hi >= 1) { Bi += Ai * Bo; Ai *= Ao; } }
      { float Ao = __shfl(Ai, (lane - 32) & 63), Bo = __shfl(Bi, (lane - 32) & 63);
        if (hi >= 2) { Bi += Ai * Bo; Ai *= Ao; } }
      float Ae1 = __shfl(Ai, (lane - 16) & 63), Be1 = __shfl(Bi, (lane - 16) & 63);
      if (hi == 0) { Ae1 = 1.f; Be1 = 0.f; }
      float At = __shfl(Ai, fr + 48), Bt = __shfl(Bi, fr + 48);  // total of s0..15
      float Ai2 = A2, Bi2 = B2;
      { float Ao = __shfl(Ai2, (lane - 16) & 63), Bo = __shfl(Bi2, (lane - 16) & 63);
        if (hi >= 1) { Bi2 += Ai2 * Bo; Ai2 *= Ao; } }
      { float Ao = __shfl(Ai2, (lane - 32) & 63), Bo = __shfl(Bi2, (lane - 32) & 63);
        if (hi >= 2) { Bi2 += Ai2 * Bo; Ai2 *= Ao; } }
      float Ae2 = __shfl(Ai2, (lane - 16) & 63), Be2 = __shfl(Bi2, (lane - 16) & 63);
      if (hi == 0) { Ae2 = 1.f; Be2 = 0.f; }
      const float Ax2 = Ae2 * At;            // prefix for mm=1 seg = excl2 ∘ total1
      const float Bx2 = Be2 + Ae2 * Bt;
      // replay + store hl/ap per position (plain stores: L2 merges 32B halves)
      const int d = dcol0 + n * 16;
      size_t rr = (rowg0 + kap * 32 + hi * 4) * 1024 + d;
      float ap = Ae1, hl = Be1;
#pragma unroll
      for (int i = 0; i < 4; ++i) {
        hl = a_[0][i] * hl + b_[0][i]; ap *= a_[0][i];
        HLp[rr] = f2bf(hl);
        APp[rr] = f2bf(ap);
        rr += 1024;
      }
      rr = (rowg0 + kap * 32 + 16 + hi * 4) * 1024 + d;
      ap = Ax2; hl = Bx2;
#pragma unroll
      for (int i = 0; i < 4; ++i) {
        hl = a_[1][i] * hl + b_[1][i]; ap *= a_[1][i];
        HLp[rr] = f2bf(hl);
        APp[rr] = f2bf(ap);
        rr += 1024;
      }
    }
  }
}

// ---------- scan phase 2: carry chain over chunk totals --------------------
// Chunk totals ARE the s==31 elements of hl/ap. Rewrites HL[s=31] with the
// inclusive carry H[c] (= final output at s=31; = carry for chunk c+1).
__global__ __launch_bounds__(256) void k_scan2(unsigned short* __restrict__ HL,
                                               const unsigned short* __restrict__ AP) {
  const int gid = blockIdx.x * 256 + threadIdx.x;   // 0..2047
  const int b = gid >> 8;
  const int d0 = (gid & 255) << 2;
  float c0 = 0.f, c1 = 0.f, c2 = 0.f, c3 = 0.f;
  for (int c = 0; c < CCH; ++c) {
    size_t off = ((size_t)b * S_ + (size_t)c * LCH + 31) * 1024 + d0;
    ushort4 hu = *reinterpret_cast<const ushort4*>(HL + off);
    ushort4 au = *reinterpret_cast<const ushort4*>(AP + off);
    c0 = fmaf(bf2f(au.x), c0, bf2f(hu.x));
    c1 = fmaf(bf2f(au.y), c1, bf2f(hu.y));
    c2 = fmaf(bf2f(au.z), c2, bf2f(hu.z));
    c3 = fmaf(bf2f(au.w), c3, bf2f(hu.w));
    ushort4 o; o.x = f2bf(c0); o.y = f2bf(c1); o.z = f2bf(c2); o.w = f2bf(c3);
    *reinterpret_cast<ushort4*>(HL + off) = o;
  }
}

// ---------- scan phase 3: out = hl + ap * carry ----------------------------
__global__ __launch_bounds__(256) void k_scan3(const unsigned short* __restrict__ HL,
                                               const unsigned short* __restrict__ AP,
                                               float* __restrict__ out) {
  const int gid = blockIdx.x * 256 + threadIdx.x;
  const int c = blockIdx.y;
  const int b = gid >> 8;
  const int d0 = (gid & 255) << 2;
  const size_t rbase = (size_t)b * S_ + (size_t)c * LCH;
  float4 carry = {0.f, 0.f, 0.f, 0.f};
  if (c > 0) {
    ushort4 cu = *reinterpret_cast<const ushort4*>(HL + (rbase - 1) * 1024 + d0);
    carry.x = bf2f(cu.x); carry.y = bf2f(cu.y); carry.z = bf2f(cu.z); carry.w = bf2f(cu.w);
  }
  size_t off = rbase * 1024 + d0;
#pragma unroll 8
  for (int s = 0; s < LCH - 1; ++s) {
    ushort4 hu = *reinterpret_cast<const ushort4*>(HL + off);
    ushort4 au = *reinterpret_cast<const ushort4*>(AP + off);
    float4 o;
    o.x = fmaf(bf2f(au.x), carry.x, bf2f(hu.x));
    o.y = fmaf(bf2f(au.y), carry.y, bf2f(hu.y));
    o.z = fmaf(bf2f(au.z), carry.z, bf2f(hu.z));
    o.w = fmaf(bf2f(au.w), carry.w, bf2f(hu.w));
    *reinterpret_cast<float4*>(out + off) = o;
    off += 1024;
  }
  // s == 31: HL already holds the final (inclusive-carry) value from k_scan2
  ushort4 hu = *reinterpret_cast<const ushort4*>(HL + off);
  float4 o;
  o.x = bf2f(hu.x); o.y = bf2f(hu.y); o.z = bf2f(hu.z); o.w = bf2f(hu.w);
  *reinterpret_cast<float4*>(out + off) = o;
}

extern "C" void kernel_launch(void* const* d_in, const int* in_sizes, int n_in,
                              void* d_out, int out_size, void* d_ws, size_t ws_size,
                              hipStream_t stream) {
  const float* x = (const float*)d_in[0];   // [8,4096,1024] f32
  const float* W = (const float*)d_in[1];   // [2048,1024]  f32
  float* out = (float*)d_out;               // [8,4096,1024] f32

  unsigned char* w = (unsigned char*)d_ws;
  // layout (= R8's proven 196 MiB): xb(64MB) | wb(4MB) | HL(64MB) | AP(64MB)
  unsigned short* xb  = (unsigned short*)(w);
  unsigned short* wb  = (unsigned short*)(w + 67108864);
  unsigned short* HLp = (unsigned short*)(w + 71303168);
  unsigned short* APp = (unsigned short*)(w + 138412032);

  k_cvt2<<<4096, 256, 0, stream>>>(x, W, xb, wb);
  k_gemm<<<(M_ / 256) * 16, 512, 0, stream>>>(xb, wb, HLp, APp);
  k_scan2<<<8, 256, 0, stream>>>(HLp, APp);
  k_scan3<<<dim3(8, CCH), 256, 0, stream>>>(HLp, APp, out);
}